// Round 7
// baseline (1373.320 us; speedup 1.0000x reference)
//
#include <hip/hip_runtime.h>
#include <stdint.h>

// ---------------------------------------------------------------------------
// out = x @ nf4_quant_dequant(w).T
//   x: [M=16384, K=4096] fp32,  w: [N=4096, K=4096] fp32,  out: [M, N] fp32
// Plan: (1) prep kernel: NF4 fake-quant w -> bf16 (w-only; x is NOT cast).
//       (2) bf16 MFMA GEMM 256x256/BK=64/8 waves, 8-phase schedule.
//           A (=x) is read fp32 and converted in-kernel: reg-stage
//           (8 dwordx4 loads issued 2 phases early) -> cvt -> swizzled
//           ds_write inside the cluster (barrier-separated from prior
//           readers; ds_write lands fast, unlike gld16's ~900cy DMA).
//           B (=wdq) stays global_load_lds with pre-swizzled source.
//           vmcnt ring: VMW(4)@P3 retires A(T2); VMW(4)@P7 retires B(T2)+A(T3).
//           T1 XCD swizzle, T2 LDS XOR swizzle, T5 setprio, nt C stores.
// ws usage: wdq (33.5 MB) only.
// ---------------------------------------------------------------------------

typedef __bf16 bf16x8 __attribute__((ext_vector_type(8)));
typedef float f32x4 __attribute__((ext_vector_type(4)));  // native vec

constexpr float NF4_CODE[16] = {
    -1.0f, -0.6961928009986877f, -0.5250730514526367f, -0.39491748809814453f,
    -0.28444138169288635f, -0.18477343022823334f, -0.09105003625154495f, 0.0f,
    0.07958029955625534f, 0.16093020141124725f, 0.24611230194568634f,
    0.33791524171829224f, 0.44070982933044434f, 0.5626170039176941f,
    0.7229568362236023f, 1.0f};
constexpr float NF4_BND[15] = {
    0.5f * (NF4_CODE[0] + NF4_CODE[1]),   0.5f * (NF4_CODE[1] + NF4_CODE[2]),
    0.5f * (NF4_CODE[2] + NF4_CODE[3]),   0.5f * (NF4_CODE[3] + NF4_CODE[4]),
    0.5f * (NF4_CODE[4] + NF4_CODE[5]),   0.5f * (NF4_CODE[5] + NF4_CODE[6]),
    0.5f * (NF4_CODE[6] + NF4_CODE[7]),   0.5f * (NF4_CODE[7] + NF4_CODE[8]),
    0.5f * (NF4_CODE[8] + NF4_CODE[9]),   0.5f * (NF4_CODE[9] + NF4_CODE[10]),
    0.5f * (NF4_CODE[10] + NF4_CODE[11]), 0.5f * (NF4_CODE[11] + NF4_CODE[12]),
    0.5f * (NF4_CODE[12] + NF4_CODE[13]), 0.5f * (NF4_CODE[13] + NF4_CODE[14]),
    0.5f * (NF4_CODE[14] + NF4_CODE[15])};

__device__ __forceinline__ unsigned short f2bf(float f) {
  unsigned int u = __float_as_uint(f);
  u += 0x7fffu + ((u >> 16) & 1u);
  return (unsigned short)(u >> 16);
}

// ---------------------------------------------------------------------------
// Prep: NF4 fake quant-dequant of w, fp32 -> bf16 bits (verified r4/r6 form).
// One scale superblock (16384 floats) per block; fully coalesced.
// ---------------------------------------------------------------------------
__global__ __launch_bounds__(256) void prep(const float* __restrict__ w,
                                            unsigned short* __restrict__ wdq) {
  __shared__ float s_am[256];
  __shared__ float s_red[4];
  __shared__ float s_code[16];
  const int t = threadIdx.x;
  if (t < 16) s_code[t] = NF4_CODE[t];
  const size_t base = (size_t)blockIdx.x * 16384;
  const f32x4* src = (const f32x4*)(w + base);

  f32x4 v[16];
#pragma unroll
  for (int k = 0; k < 16; ++k) {
    v[k] = __builtin_nontemporal_load(src + k * 256 + t);
    float m = fmaxf(fmaxf(fabsf(v[k][0]), fabsf(v[k][1])),
                    fmaxf(fabsf(v[k][2]), fabsf(v[k][3])));
    m = fmaxf(m, __shfl_xor(m, 1));
    m = fmaxf(m, __shfl_xor(m, 2));
    m = fmaxf(m, __shfl_xor(m, 4));
    m = fmaxf(m, __shfl_xor(m, 8));
    if ((t & 15) == 0) s_am[k * 16 + (t >> 4)] = m;  // quant block id
  }
  __syncthreads();
  float m = s_am[t];
  m = fmaxf(m, __shfl_xor(m, 1));
  m = fmaxf(m, __shfl_xor(m, 2));
  m = fmaxf(m, __shfl_xor(m, 4));
  m = fmaxf(m, __shfl_xor(m, 8));
  m = fmaxf(m, __shfl_xor(m, 16));
  m = fmaxf(m, __shfl_xor(m, 32));
  if ((t & 63) == 0) s_red[t >> 6] = m;
  __syncthreads();
  const float s_amax =
      fmaxf(fmaxf(s_red[0], s_red[1]), fmaxf(s_red[2], s_red[3]));
  const float sa = (s_amax == 0.f) ? 1.f : s_amax;

#pragma unroll
  for (int k = 0; k < 16; ++k) {
    const float am = s_am[k * 16 + (t >> 4)];
    float q8 = rintf(am / sa * 127.f);
    q8 = fminf(fmaxf(q8, -127.f), 127.f);
    const float scale = (q8 / 127.f) * sa;
    const float safe_am = (am == 0.f) ? 1.f : am;
    unsigned r[4];
#pragma unroll
    for (int e = 0; e < 4; ++e) {
      const float norm = v[k][e] / safe_am;
      int idx = 0;
#pragma unroll
      for (int j = 0; j < 15; ++j) idx += (NF4_BND[j] < norm) ? 1 : 0;
      r[e] = (unsigned)f2bf(s_code[idx] * scale);
    }
    uint2 o;
    o.x = r[0] | (r[1] << 16);
    o.y = r[2] | (r[3] << 16);
    ((uint2*)(wdq + base))[k * 256 + t] = o;
  }
}

// ---------------------------------------------------------------------------
// GEMM: C[M,N] = A_f32[M,K] * Bt_bf16[N,K]^T, fp32 out.
// 256x256 tile, BK=64, 512 thr (8 waves = 2Mx4N, wave = 128x64 via 8x4 of
// 16x16x32 MFMA). 8 phases / 2 K-tiles per iter (T0=b0, T1=b1).
//
//   phase | MM (tile) | RD (next set)  | stage action
//   P1    | (0,0) T0  | B-hi(T0)       | issue A(T2) loads (8 dwordx4)
//   P2    | (0,1) T0  | A-hi(T0)       | STGB B(T2)->b0.B (4 gld16)
//   P3    | (1,0) T0  | B-lo(T1)       | VMW(4); cvt+ds_write A(T2)->b0.A
//   P4    | (1,1) T0  | A-lo(T1)       | lgkm0 (publish A-writes)
//   P5    | (0,0) T1  | B-hi(T1)       | issue A(T3) loads
//   P6    | (0,1) T1  | A-hi(T1)       | STGB B(T3)->b1.B
//   P7    | (1,0) T1  | B-lo(T2)       | VMW(4); cvt+ds_write A(T3)->b1.A
//   P8    | (1,1) T1  | A-lo(T2)       | lgkm0
//
// vmcnt stream/iter: A2@P1(8), B2@P2(4), A3@P5(8), B3@P6(4).
//   VMW(4)@P3: retires A2 + B3(prev) (cvt input + b1.B reads valid).
//   VMW(4)@P7: retires B2 + A3 (b0.B reads valid + cvt input).
// A-writes are INSIDE the cluster (post-BARX) so the previous phase's
// readers of that region are barrier-separated (ds_write lands fast —
// r5 lesson: this WAR window is real for ds_write, unlike gld16).
// Publication: lgkm0 before P4/P8 barrier; first read 4 barriers later.
// B WAR window (gld16 issued pre-BARX vs same-region reads in previous
// cluster) is the r4/r6-verified pattern (DMA lands ~900cy later).
//
// LDS (128 KiB): [buf(2)][A/B(2)][half(2)][128 rows][64 k] bf16, T2 swizzle
// (slot s at row r holds k-chunk s^(r&7)). B: pre-swizzled global source +
// linear gld16 dest. A: linear global source + swizzled ds_write dest.
// ---------------------------------------------------------------------------

__device__ __forceinline__ void gld16(const unsigned short* g, unsigned short* l) {
  __builtin_amdgcn_global_load_lds(
      (__attribute__((address_space(1))) void*)g,
      (__attribute__((address_space(3))) void*)l, 16, 0, 0);
}

#define BARX                                                                   \
  do {                                                                         \
    asm volatile("" ::: "memory");                                             \
    __builtin_amdgcn_s_barrier();                                              \
    asm volatile("" ::: "memory");                                             \
  } while (0)
#define VMW(n) asm volatile("s_waitcnt vmcnt(" #n ")" ::: "memory")
#define LGKM0 asm volatile("s_waitcnt lgkmcnt(0)" ::: "memory")
#define SCHB __builtin_amdgcn_sched_barrier(0)
#define SP1 __builtin_amdgcn_s_setprio(1)
#define SP0 __builtin_amdgcn_s_setprio(0)

#define STGB(buf, hf, ks)                                                      \
  do {                                                                         \
    const unsigned short* g_ = gB0 + (size_t)(hf)*HOFF + (size_t)(ks);         \
    unsigned short* l_ = lds + (buf)*32768 + 16384 + (hf)*8192 + wvoff;        \
    gld16(g_, l_);                                                             \
    gld16(g_ + 64 * (size_t)K, l_ + 4096);                                     \
  } while (0)

#define LDA(ks)                                                                \
  do {                                                                         \
    const f32x4* g_ = (const f32x4*)(gAx + (size_t)(ks));                      \
    _Pragma("unroll") for (int q = 0; q < 8; ++q) rA[q] = g_[q];               \
  } while (0)

#define CVTW(buf)                                                              \
  do {                                                                         \
    _Pragma("unroll") for (int c = 0; c < 4; ++c) {                            \
      bf16x8 wv;                                                               \
      _Pragma("unroll") for (int e = 0; e < 4; ++e) {                          \
        wv[e] = (__bf16)rA[c * 2][e];                                          \
        wv[e + 4] = (__bf16)rA[c * 2 + 1][e];                                  \
      }                                                                        \
      const int slot = (((lane & 1) << 2) + c) ^ r7;                           \
      *(bf16x8*)(ldsA + (buf)*32768 + slot * 8) = wv;                          \
    }                                                                          \
  } while (0)

#define RDA(buf, mh, ks)                                                       \
  do {                                                                         \
    _Pragma("unroll") for (int i4 = 0; i4 < 4; ++i4) {                         \
      afr[i4][ks] = *(const bf16x8*)(pa + (buf)*32768 + (mh)*4096 +            \
                                     i4 * 1024 + ((ks) ? aoff1 : aoff0));      \
    }                                                                          \
  } while (0)

#define RDB(buf, nh, ks)                                                       \
  do {                                                                         \
    _Pragma("unroll") for (int j2 = 0; j2 < 2; ++j2) {                         \
      bfr[(nh)*2 + j2][ks] = *(const bf16x8*)(pb + (buf)*32768 + (nh)*2048 +   \
                                              j2 * 1024 +                      \
                                              ((ks) ? aoff1 : aoff0));         \
    }                                                                          \
  } while (0)

#define MMH(mh, nh, ks)                                                        \
  do {                                                                         \
    _Pragma("unroll") for (int i4 = 0; i4 < 4; ++i4) {                         \
      _Pragma("unroll") for (int j2 = 0; j2 < 2; ++j2) {                       \
        acc[(mh)*4 + i4][(nh)*2 + j2] =                                        \
            __builtin_amdgcn_mfma_f32_16x16x32_bf16(                           \
                afr[i4][ks], bfr[(nh)*2 + j2][ks],                             \
                acc[(mh)*4 + i4][(nh)*2 + j2], 0, 0, 0);                       \
      }                                                                        \
    }                                                                          \
  } while (0)

__global__ __launch_bounds__(512, 2) void gemm8p(const float* __restrict__ A,
                                                 const unsigned short* __restrict__ Bt,
                                                 float* __restrict__ C,
                                                 int M, int N, int K) {
  __shared__ __align__(16) unsigned short lds[65536];  // 128 KiB

  const int t = threadIdx.x;
  const int wave = t >> 6;
  const int lane = t & 63;

  // --- T1: bijective XCD-aware block swizzle ---
  const int nbx = N >> 8;
  const int nwg = nbx * (M >> 8);
  const int q8 = nwg >> 3, r8 = nwg & 7;
  const int xcd = (int)blockIdx.x & 7, off = (int)blockIdx.x >> 3;
  const int wg =
      (xcd < r8 ? xcd * (q8 + 1) : r8 * (q8 + 1) + (xcd - r8) * q8) + off;
  const int bm = (wg / nbx) << 8;
  const int bn = (wg % nbx) << 8;

  // --- B staging (gld16, pre-swizzled global source, linear LDS dest) ---
  const size_t HOFF = (size_t)128 * K;            // half-tile row offset
  const int srow = wave * 8 + (lane >> 3);        // local row in [0,64)
  const int sj = (lane & 7) ^ (lane >> 3);        // inverse-swizzled k-chunk
  const unsigned short* gB0 = Bt + (size_t)(bn + srow) * K + sj * 8;
  const int wvoff = wave * 512;                   // LDS chunk base (elems)

  // --- A staging (fp32 reg-load -> cvt -> swizzled ds_write) ---
  // lane pair owns one tile row: row = wave*32 + (lane>>1), k-half by lane&1
  const int arowg = wave * 32 + (lane >> 1);      // tile row [0,256)
  const float* gAx = A + (size_t)(bm + arowg) * K + (lane & 1) * 32;
  const int r7 = arowg & 7;
  unsigned short* ldsA =
      lds + ((arowg >> 7) * 8192) + (arowg & 127) * 64;  // + buf*32768 + slot*8
  f32x4 rA[8];

  // --- compute addressing ---
  const int wm = wave >> 2;   // m half owned by this wave
  const int wn = wave & 3;    // n quarter owned by this wave
  const int quad = lane >> 4;
  const int lrow = lane & 15;
  const int s0 = quad ^ (lrow & 7);               // swizzled chunk, ks=0
  const int aoff0 = lrow * 64 + s0 * 8;
  const int aoff1 = lrow * 64 + (s0 ^ 4) * 8;     // ks=1
  const unsigned short* pa = lds + wm * 8192;
  const unsigned short* pb = lds + 16384 + (wn >> 1) * 8192 + (wn & 1) * 4096;

  f32x4 acc[8][4];
  const f32x4 zero = {0.f, 0.f, 0.f, 0.f};
#pragma unroll
  for (int i = 0; i < 8; ++i)
#pragma unroll
    for (int j = 0; j < 4; ++j) acc[i][j] = zero;

  bf16x8 afr[4][2];   // current A sub-half (rotates lo->hi->lo' ...)
  bf16x8 bfr[4][2];   // [0..1]=B-lo, [2..3]=B-hi of wave's quarter

  // --- prologue: T0 -> b0 (A cvt + B gld16), T1 -> b1; prime lo-fragments ---
  LDA(0);                                     // A(T0): vm 1-8
  STGB(0, 0, 0); STGB(0, 1, 0);               // b0.B:  vm 9-12
  STGB(1, 0, 64); STGB(1, 1, 64);             // b1.B:  vm 13-16
  VMW(8);                                     // A(T0) retired
  CVTW(0);                                    // b0.A <- T0
  LDA(64);                                    // A(T1), regs reused
  VMW(0);                                     // all retired (incl. b0/b1.B)
  CVTW(1);                                    // b1.A <- T1
  LGKM0; BARX;
  RDA(0, 0, 0); RDA(0, 0, 1);                 // prime afr = A-lo(T0)
  RDB(0, 0, 0); RDB(0, 0, 1);                 // prime bfr[0..1] = B-lo(T0)

  const int niter = K >> 7;  // 2 K-tiles per iteration
  for (int it = 0; it < niter; ++it) {
    const int kt = it << 7;
    int kc2 = kt + 128; if (kc2 > K - 64) kc2 = K - 64;  // T2 (tail: dummy)
    int kc3 = kt + 192; if (kc3 > K - 64) kc3 = K - 64;  // T3 (tail: dummy)

    // P1: MM(0,0)T0 | RD B-hi(T0) | issue A(T2) loads
    LDA(kc2); BARX;
    SP1; MMH(0, 0, 0); RDB(0, 1, 0); MMH(0, 0, 1); RDB(0, 1, 1); SP0;
    // P2: MM(0,1)T0 | RD A-hi(T0) | stage B(T2) -> b0.B
    STGB(0, 0, kc2); STGB(0, 1, kc2); BARX;
    SP1; MMH(0, 1, 0); RDA(0, 1, 0); MMH(0, 1, 1); RDA(0, 1, 1); SP0;
    // P3: MM(1,0)T0 | RD B-lo(T1) | cvt+write A(T2) -> b0.A (post-BARX!)
    VMW(4); BARX; SCHB; CVTW(0);
    SP1; MMH(1, 0, 0); RDB(1, 0, 0); MMH(1, 0, 1); RDB(1, 0, 1); SP0;
    // P4: MM(1,1)T0 | RD A-lo(T1) | publish A-writes
    LGKM0; BARX;
    SP1; MMH(1, 1, 0); RDA(1, 0, 0); MMH(1, 1, 1); RDA(1, 0, 1); SP0;
    // P5: MM(0,0)T1 | RD B-hi(T1) | issue A(T3) loads
    LDA(kc3); BARX;
    SP1; MMH(0, 0, 0); RDB(1, 1, 0); MMH(0, 0, 1); RDB(1, 1, 1); SP0;
    // P6: MM(0,1)T1 | RD A-hi(T1) | stage B(T3) -> b1.B
    STGB(1, 0, kc3); STGB(1, 1, kc3); BARX;
    SP1; MMH(0, 1, 0); RDA(1, 1, 0); MMH(0, 1, 1); RDA(1, 1, 1); SP0;
    // P7: MM(1,0)T1 | RD B-lo(T2) | cvt+write A(T3) -> b1.A
    VMW(4); BARX; SCHB; CVTW(1);
    SP1; MMH(1, 0, 0); RDB(0, 0, 0); MMH(1, 0, 1); RDB(0, 0, 1); SP0;
    // P8: MM(1,1)T1 | RD A-lo(T2) | publish A-writes
    LGKM0; BARX;
    SP1; MMH(1, 1, 0); RDA(0, 0, 0); MMH(1, 1, 1); RDA(0, 0, 1); SP0;
  }

  // drain outstanding B-DMA before block exit
  VMW(0);

  // epilogue: D[row=quad*4+r][col=lrow] per 16x16 tile; nontemporal stores
  const int crow = bm + wm * 128 + quad * 4;
  const int ccol = bn + wn * 64 + lrow;
#pragma unroll
  for (int i = 0; i < 8; ++i) {
#pragma unroll
    for (int j = 0; j < 4; ++j) {
      float* cp = C + (size_t)(crow + i * 16) * N + (ccol + j * 16);
#pragma unroll
      for (int r = 0; r < 4; ++r)
        __builtin_nontemporal_store(acc[i][j][r], cp + (size_t)r * N);
    }
  }
}

// ---------------------------------------------------------------------------
extern "C" void kernel_launch(void* const* d_in, const int* in_sizes, int n_in,
                              void* d_out, int out_size, void* d_ws, size_t ws_size,
                              hipStream_t stream) {
  const float* x = (const float*)d_in[0];   // [M, K]
  const float* w = (const float*)d_in[1];   // [N, K]
  const int K = 4096;
  const int M = in_sizes[0] / K;            // 16384
  const int N = in_sizes[1] / K;            // 4096

  unsigned short* wdq = (unsigned short*)d_ws;  // [N*K] bf16 bits (33.5 MB)

  prep<<<in_sizes[1] / 16384, 256, 0, stream>>>(w, wdq);
  dim3 grid((N / 256) * (M / 256));
  gemm8p<<<grid, 512, 0, stream>>>(x, wdq, (float*)d_out, M, N, K);
}